// Round 5
// baseline (301.131 us; speedup 1.0000x reference)
//
#include <hip/hip_runtime.h>
#include <hip/hip_cooperative_groups.h>
#include <stdint.h>

namespace cg = cooperative_groups;

#define NS_ 4096
#define M_  8192
#define D_  256
#define TEMP 0.07f
#define EXP_SCALE 20.61707212818536f   // log2(e)/0.07 : exp(sim/T) = exp2(sim*EXP_SCALE)
#define LN2 0.6931471805599453f

typedef short bf16x8 __attribute__((ext_vector_type(8)));
typedef float f32x4  __attribute__((ext_vector_type(4)));
typedef unsigned short ushortx4 __attribute__((ext_vector_type(4)));

static __device__ inline unsigned short f2bf(float x) {
    unsigned u = __float_as_uint(x);
    u += 0x7fffu + ((u >> 16) & 1u);
    return (unsigned short)(u >> 16);
}

static __device__ inline float cleanf(float v) {
    return __builtin_isfinite(v) ? v : 0.0f;
}

// async 16B global -> LDS (lane-contiguous LDS destination required)
#define LDS_LOAD16(gp, lp) \
    __builtin_amdgcn_global_load_lds((const __attribute__((address_space(1))) uint32_t*)(gp), \
                                     (__attribute__((address_space(3))) uint32_t*)(lp), 16, 0, 0)

#define STORE_AGENT_U64(p, v) \
    __hip_atomic_store((uint64_t*)(p), (v), __ATOMIC_RELAXED, __HIP_MEMORY_SCOPE_AGENT)
#define STORE_AGENT_F32(p, v) \
    __hip_atomic_store((float*)(p), (v), __ATOMIC_RELAXED, __HIP_MEMORY_SCOPE_AGENT)

// ================= FUSED cooperative kernel: normalize -> gridsync -> GEMM -> epilogue ==
// grid = 512 blocks x 256 thr (2 blocks/CU co-resident: 33KB LDS, 128 VGPR target).
// Phase 1: each block normalizes 8 row-pairs (2 per wave); F/pos/denom written with
// AGENT-scope stores (per-XCD L2s are not coherent; plain stores would sit dirty in the
// writer XCD's L2, invisible to reader XCDs within the same kernel).
// Phase 2: R0's proven kgemm body (single 32KB buffer, 4 A-chunks + 8 B-groups,
// XOR-swizzled global_load_lds staging, diag-masked exp2, per-row atomics).
// Epilogue after 2nd grid.sync: blocks 0..31 do the log-sum finishers (no cnt fan-in).
__global__ __launch_bounds__(256, 2) void kfused(const float* __restrict__ z1,
                                                 const float* __restrict__ z2,
                                                 short* __restrict__ F,
                                                 float* __restrict__ pos,
                                                 float* __restrict__ denom,
                                                 float* __restrict__ out) {
    __shared__ short Bl[64 * 256];   // 32 KB staging tile [row][k], 16B chunks swizzled
    __shared__ float red[4];

    const int tid  = threadIdx.x;
    const int lane = tid & 63;
    const int wave = tid >> 6;
    const int bid  = blockIdx.x;

    // ---------------- phase 1: clean + normalize -> bf16 F (agent stores), fp32 pos ----
    #pragma unroll
    for (int pp = 0; pp < 2; ++pp) {
        const int i = bid * 8 + wave * 2 + pp;
        float4 a = ((const float4*)(z1 + (size_t)i * D_))[lane];
        float4 b = ((const float4*)(z2 + (size_t)i * D_))[lane];
        a.x = cleanf(a.x); a.y = cleanf(a.y); a.z = cleanf(a.z); a.w = cleanf(a.w);
        b.x = cleanf(b.x); b.y = cleanf(b.y); b.z = cleanf(b.z); b.w = cleanf(b.w);

        float s1 = a.x*a.x + a.y*a.y + a.z*a.z + a.w*a.w;
        float s2 = b.x*b.x + b.y*b.y + b.z*b.z + b.w*b.w;
        float dp = a.x*b.x + a.y*b.y + a.z*b.z + a.w*b.w;
        #pragma unroll
        for (int m = 1; m < 64; m <<= 1) {
            s1 += __shfl_xor(s1, m);
            s2 += __shfl_xor(s2, m);
            dp += __shfl_xor(dp, m);
        }
        const float inv1 = 1.0f / fmaxf(sqrtf(s1), 1e-12f);
        const float inv2 = 1.0f / fmaxf(sqrtf(s2), 1e-12f);

        uint64_t u1 = (uint64_t)f2bf(a.x * inv1)
                    | ((uint64_t)f2bf(a.y * inv1) << 16)
                    | ((uint64_t)f2bf(a.z * inv1) << 32)
                    | ((uint64_t)f2bf(a.w * inv1) << 48);
        uint64_t u2 = (uint64_t)f2bf(b.x * inv2)
                    | ((uint64_t)f2bf(b.y * inv2) << 16)
                    | ((uint64_t)f2bf(b.z * inv2) << 32)
                    | ((uint64_t)f2bf(b.w * inv2) << 48);
        STORE_AGENT_U64((uint64_t*)(F + (size_t)i * D_) + lane, u1);
        STORE_AGENT_U64((uint64_t*)(F + (size_t)(i + NS_) * D_) + lane, u2);
        if (lane == 0) STORE_AGENT_F32(pos + i, dp * inv1 * inv2);
    }
    if (tid < 16) STORE_AGENT_F32(denom + bid * 16 + tid, 0.0f);  // 512*16 = 8192 rows
    if (bid == 0 && tid == 0) STORE_AGENT_F32(out, 0.0f);
    __threadfence();
    cg::this_grid().sync();

    // ---------------- phase 2: fused sim-GEMM + row exp-sums (R0 body) ------------------
    const int rtile = bid >> 4;          // 32 rtiles (256 rows)
    const int cq    = bid & 15;          // 16 col-blocks (512 cols)
    const int R0 = rtile * 256;
    const int C0 = cq * 512;
    const int c16  = lane & 15;
    const int quad = lane >> 4;
    const int swz  = c16 & 7;

    // staging source offsets (shorts, relative to 64-row chunk base), XOR-swizzled
    int goff[8];
    #pragma unroll
    for (int r2 = 0; r2 < 8; ++r2) {
        int c    = tid + r2 * 256;
        int row  = c >> 5;
        int kg   = (c & 31) ^ (row & 7);
        goff[r2] = row * D_ + kg * 8;
    }

    // A prologue: 4 chunks of 64 rows; wave w reads local rows w*16+c16 of each chunk
    bf16x8 afrag[4][8];
    const int arow_l = wave * 16 + c16;
    #pragma unroll
    for (int ch = 0; ch < 4; ++ch) {
        __syncthreads();
        const short* ga = F + (size_t)(R0 + ch * 64) * D_;
        #pragma unroll
        for (int r2 = 0; r2 < 8; ++r2)
            LDS_LOAD16(ga + goff[r2], Bl + (tid + r2 * 256) * 8);
        __syncthreads();
        #pragma unroll
        for (int ks = 0; ks < 8; ++ks)
            afrag[ch][ks] = *(const bf16x8*)(Bl + arow_l * 256 +
                                             (((ks * 4 + quad) ^ (arow_l & 7)) * 8));
    }

    float accexp[4][4];
    #pragma unroll
    for (int s = 0; s < 4; ++s)
        #pragma unroll
        for (int r = 0; r < 4; ++r) accexp[s][r] = 0.0f;

    // main loop: 8 B-groups of 64 cols
    for (int it = 0; it < 8; ++it) {
        __syncthreads();                       // previous tile's reads done
        const short* gb = F + (size_t)(C0 + it * 64) * D_;
        #pragma unroll
        for (int r2 = 0; r2 < 8; ++r2)
            LDS_LOAD16(gb + goff[r2], Bl + (tid + r2 * 256) * 8);
        __syncthreads();                       // staging complete

        #pragma unroll
        for (int sub = 0; sub < 4; ++sub) {
            const int tc = sub * 16 + c16;     // tile col owned by this lane
            bf16x8 bfrag[8];
            #pragma unroll
            for (int ks = 0; ks < 8; ++ks)
                bfrag[ks] = *(const bf16x8*)(Bl + tc * 256 +
                                             (((ks * 4 + quad) ^ swz) * 8));
            f32x4 acc[4];
            #pragma unroll
            for (int s = 0; s < 4; ++s) acc[s] = (f32x4){0.f, 0.f, 0.f, 0.f};
            #pragma unroll
            for (int ks = 0; ks < 8; ++ks)
                #pragma unroll
                for (int s = 0; s < 4; ++s)
                    acc[s] = __builtin_amdgcn_mfma_f32_16x16x32_bf16(
                        afrag[s][ks], bfrag[ks], acc[s], 0, 0, 0);

            const int colbase = C0 + it * 64 + sub * 16;
            #pragma unroll
            for (int s = 0; s < 4; ++s) {
                const int rowbase = R0 + s * 64 + wave * 16;
                if (colbase != rowbase) {            // uniform fast path
                    #pragma unroll
                    for (int r = 0; r < 4; ++r)
                        accexp[s][r] += __builtin_amdgcn_exp2f(acc[s][r] * EXP_SCALE);
                } else {                             // diagonal 16x16 tile
                    #pragma unroll
                    for (int r = 0; r < 4; ++r) {
                        float e = __builtin_amdgcn_exp2f(acc[s][r] * EXP_SCALE);
                        if (c16 == quad * 4 + r) e = 0.0f;
                        accexp[s][r] += e;
                    }
                }
            }
        }
    }

    // row sums across the 16 lanes holding each row, one atomic per row
    #pragma unroll
    for (int s = 0; s < 4; ++s)
        #pragma unroll
        for (int r = 0; r < 4; ++r) {
            float v = accexp[s][r];
            v += __shfl_xor(v, 1);
            v += __shfl_xor(v, 2);
            v += __shfl_xor(v, 4);
            v += __shfl_xor(v, 8);
            if (c16 == 0)
                atomicAdd(&denom[R0 + s * 64 + wave * 16 + quad * 4 + r], v);
        }

    __threadfence();
    cg::this_grid().sync();

    // ---------------- epilogue: blocks 0..31, one rtile each ----------------------------
    if (bid < 32) {
        float v = atomicAdd(&denom[bid * 256 + tid], 0.0f);   // coherent read, 256 rows
        float p = __builtin_amdgcn_logf(v) * (LN2 / (float)M_);
        #pragma unroll
        for (int m = 1; m < 64; m <<= 1) p += __shfl_xor(p, m);
        if (lane == 0) red[wave] = p;
        __syncthreads();
        if (tid == 0) atomicAdd(out, red[0] + red[1] + red[2] + red[3]);
        if (bid == 0) {
            __syncthreads();                                  // protect red reuse
            float sp = 0.0f;
            for (int ii = tid; ii < NS_; ii += 256)
                sp += atomicAdd(&pos[ii], 0.0f);              // coherent read
            #pragma unroll
            for (int m = 1; m < 64; m <<= 1) sp += __shfl_xor(sp, m);
            if (lane == 0) red[wave] = sp;
            __syncthreads();
            if (tid == 0)
                atomicAdd(out, (red[0] + red[1] + red[2] + red[3]) *
                               (-2.0f / (TEMP * (float)M_)));
        }
    }
}

// ================= FALLBACK path (R0's proven two-kernel version) =======================
__global__ __launch_bounds__(64) void knorm(const float* __restrict__ z1,
                                            const float* __restrict__ z2,
                                            short* __restrict__ F,
                                            float* __restrict__ pos,
                                            float* __restrict__ denom,
                                            int* __restrict__ cnt,
                                            float* __restrict__ out) {
    const int i = blockIdx.x;
    const int t = threadIdx.x;
    const float4* p1 = (const float4*)(z1 + (size_t)i * D_);
    const float4* p2 = (const float4*)(z2 + (size_t)i * D_);
    float4 a = p1[t], b = p2[t];
    a.x = cleanf(a.x); a.y = cleanf(a.y); a.z = cleanf(a.z); a.w = cleanf(a.w);
    b.x = cleanf(b.x); b.y = cleanf(b.y); b.z = cleanf(b.z); b.w = cleanf(b.w);

    float s1 = a.x*a.x + a.y*a.y + a.z*a.z + a.w*a.w;
    float s2 = b.x*b.x + b.y*b.y + b.z*b.z + b.w*b.w;
    float dp = a.x*b.x + a.y*b.y + a.z*b.z + a.w*b.w;
    #pragma unroll
    for (int m = 1; m < 64; m <<= 1) {
        s1 += __shfl_xor(s1, m);
        s2 += __shfl_xor(s2, m);
        dp += __shfl_xor(dp, m);
    }
    const float inv1 = 1.0f / fmaxf(sqrtf(s1), 1e-12f);
    const float inv2 = 1.0f / fmaxf(sqrtf(s2), 1e-12f);

    ushortx4 o1, o2;
    o1.x = f2bf(a.x * inv1); o1.y = f2bf(a.y * inv1); o1.z = f2bf(a.z * inv1); o1.w = f2bf(a.w * inv1);
    o2.x = f2bf(b.x * inv2); o2.y = f2bf(b.y * inv2); o2.z = f2bf(b.z * inv2); o2.w = f2bf(b.w * inv2);
    ((ushortx4*)(F + (size_t)i * D_))[t]          = o1;
    ((ushortx4*)(F + (size_t)(i + NS_) * D_))[t]  = o2;

    if (t == 0) pos[i] = dp * inv1 * inv2;
    if (t < 2)  denom[i * 2 + t] = 0.0f;
    if (i == 0 && t < 32) cnt[t] = 0;
    if (i == 0 && t == 0) out[0] = 0.0f;
}

__global__ __launch_bounds__(256, 2) void kgemm(const short* __restrict__ F,
                                                float* __restrict__ denom,
                                                int* __restrict__ cnt,
                                                const float* __restrict__ pos,
                                                float* __restrict__ out) {
    __shared__ short Bl[64 * 256];
    __shared__ int lastflag;
    __shared__ float red[4];

    const int rtile = blockIdx.x >> 4;
    const int cq    = blockIdx.x & 15;
    const int R0 = rtile * 256;
    const int C0 = cq * 512;

    const int tid  = threadIdx.x;
    const int lane = tid & 63;
    const int wave = tid >> 6;
    const int c16  = lane & 15;
    const int quad = lane >> 4;
    const int swz  = c16 & 7;

    int goff[8];
    #pragma unroll
    for (int r2 = 0; r2 < 8; ++r2) {
        int c    = tid + r2 * 256;
        int row  = c >> 5;
        int kg   = (c & 31) ^ (row & 7);
        goff[r2] = row * D_ + kg * 8;
    }

    bf16x8 afrag[4][8];
    const int arow_l = wave * 16 + c16;
    #pragma unroll
    for (int ch = 0; ch < 4; ++ch) {
        __syncthreads();
        const short* ga = F + (size_t)(R0 + ch * 64) * D_;
        #pragma unroll
        for (int r2 = 0; r2 < 8; ++r2)
            LDS_LOAD16(ga + goff[r2], Bl + (tid + r2 * 256) * 8);
        __syncthreads();
        #pragma unroll
        for (int ks = 0; ks < 8; ++ks)
            afrag[ch][ks] = *(const bf16x8*)(Bl + arow_l * 256 +
                                             (((ks * 4 + quad) ^ (arow_l & 7)) * 8));
    }

    float accexp[4][4];
    #pragma unroll
    for (int s = 0; s < 4; ++s)
        #pragma unroll
        for (int r = 0; r < 4; ++r) accexp[s][r] = 0.0f;

    for (int it = 0; it < 8; ++it) {
        __syncthreads();
        const short* gb = F + (size_t)(C0 + it * 64) * D_;
        #pragma unroll
        for (int r2 = 0; r2 < 8; ++r2)
            LDS_LOAD16(gb + goff[r2], Bl + (tid + r2 * 256) * 8);
        __syncthreads();

        #pragma unroll
        for (int sub = 0; sub < 4; ++sub) {
            const int tc = sub * 16 + c16;
            bf16x8 bfrag[8];
            #pragma unroll
            for (int ks = 0; ks < 8; ++ks)
                bfrag[ks] = *(const bf16x8*)(Bl + tc * 256 +
                                             (((ks * 4 + quad) ^ swz) * 8));
            f32x4 acc[4];
            #pragma unroll
            for (int s = 0; s < 4; ++s) acc[s] = (f32x4){0.f, 0.f, 0.f, 0.f};
            #pragma unroll
            for (int ks = 0; ks < 8; ++ks)
                #pragma unroll
                for (int s = 0; s < 4; ++s)
                    acc[s] = __builtin_amdgcn_mfma_f32_16x16x32_bf16(
                        afrag[s][ks], bfrag[ks], acc[s], 0, 0, 0);

            const int colbase = C0 + it * 64 + sub * 16;
            #pragma unroll
            for (int s = 0; s < 4; ++s) {
                const int rowbase = R0 + s * 64 + wave * 16;
                if (colbase != rowbase) {
                    #pragma unroll
                    for (int r = 0; r < 4; ++r)
                        accexp[s][r] += __builtin_amdgcn_exp2f(acc[s][r] * EXP_SCALE);
                } else {
                    #pragma unroll
                    for (int r = 0; r < 4; ++r) {
                        float e = __builtin_amdgcn_exp2f(acc[s][r] * EXP_SCALE);
                        if (c16 == quad * 4 + r) e = 0.0f;
                        accexp[s][r] += e;
                    }
                }
            }
        }
    }

    #pragma unroll
    for (int s = 0; s < 4; ++s)
        #pragma unroll
        for (int r = 0; r < 4; ++r) {
            float v = accexp[s][r];
            v += __shfl_xor(v, 1);
            v += __shfl_xor(v, 2);
            v += __shfl_xor(v, 4);
            v += __shfl_xor(v, 8);
            if (c16 == 0)
                atomicAdd(&denom[R0 + s * 64 + wave * 16 + quad * 4 + r], v);
        }

    __syncthreads();
    if (tid == 0) {
        __threadfence();
        lastflag = (atomicAdd(&cnt[rtile], 1) == 15);
    }
    __syncthreads();
    if (lastflag) {
        __threadfence();
        float v = atomicAdd(&denom[R0 + tid], 0.0f);
        float p = __builtin_amdgcn_logf(v) * (LN2 / (float)M_);
        #pragma unroll
        for (int m = 1; m < 64; m <<= 1) p += __shfl_xor(p, m);
        if (lane == 0) red[wave] = p;
        __syncthreads();
        if (tid == 0) atomicAdd(out, red[0] + red[1] + red[2] + red[3]);
        if (rtile == 0) {
            __syncthreads();
            float sp = 0.0f;
            for (int i = tid; i < NS_; i += 256) sp += pos[i];
            #pragma unroll
            for (int m = 1; m < 64; m <<= 1) sp += __shfl_xor(sp, m);
            if (lane == 0) red[wave] = sp;
            __syncthreads();
            if (tid == 0)
                atomicAdd(out, (red[0] + red[1] + red[2] + red[3]) *
                               (-2.0f / (TEMP * (float)M_)));
        }
    }
}

extern "C" void kernel_launch(void* const* d_in, const int* in_sizes, int n_in,
                              void* d_out, int out_size, void* d_ws, size_t ws_size,
                              hipStream_t stream) {
    const float* z1 = (const float*)d_in[0];
    const float* z2 = (const float*)d_in[1];

    short* F     = (short*)d_ws;                                   // 4 MB
    float* denom = (float*)((char*)d_ws + (size_t)M_ * D_ * 2);    // 32 KB
    int*   cnt   = (int*)(denom + M_);                             // 128 B
    float* pos   = (float*)(cnt + 32);                             // 16 KB
    float* outp  = (float*)d_out;

    void* args[] = { (void*)&z1, (void*)&z2, (void*)&F, (void*)&pos,
                     (void*)&denom, (void*)&outp };
    hipError_t e = hipLaunchCooperativeKernel((const void*)kfused, dim3(512), dim3(256),
                                              args, 0, stream);
    if (e != hipSuccess) {
        // fallback: proven two-kernel path
        knorm<<<NS_, 64, 0, stream>>>(z1, z2, F, pos, denom, cnt, outp);
        kgemm<<<512, 256, 0, stream>>>(F, denom, cnt, pos, outp);
    }
}

// Round 6
// 146.595 us; speedup vs baseline: 2.0542x; 2.0542x over previous
//
#include <hip/hip_runtime.h>
#include <stdint.h>

#define NS_ 4096
#define M_  8192
#define D_  256
#define TEMP 0.07f
#define EXP_SCALE 20.61707212818536f   // log2(e)/0.07 : exp(sim/T) = exp2(sim*EXP_SCALE)
#define LN2 0.6931471805599453f

typedef short bf16x8 __attribute__((ext_vector_type(8)));
typedef float f32x4  __attribute__((ext_vector_type(4)));
typedef unsigned short ushortx4 __attribute__((ext_vector_type(4)));

static __device__ inline unsigned short f2bf(float x) {
    unsigned u = __float_as_uint(x);
    u += 0x7fffu + ((u >> 16) & 1u);
    return (unsigned short)(u >> 16);
}

static __device__ inline float cleanf(float v) {
    return __builtin_isfinite(v) ? v : 0.0f;
}

// async 16B global -> LDS (lane-contiguous LDS destination required)
#define LDS_LOAD16(gp, lp) \
    __builtin_amdgcn_global_load_lds((const __attribute__((address_space(1))) uint32_t*)(gp), \
                                     (__attribute__((address_space(3))) uint32_t*)(lp), 16, 0, 0)

// ---------------- Kernel 1: clean + normalize -> bf16 F, fp32 pos[]; zero denom/cnt/out -
// grid = NS_/4, block = 256 (one wave per paired row; 4 row-pairs per block)
__global__ __launch_bounds__(256) void knorm(const float* __restrict__ z1,
                                             const float* __restrict__ z2,
                                             short* __restrict__ F,
                                             float* __restrict__ pos,
                                             float* __restrict__ denom,
                                             int* __restrict__ cnt,
                                             float* __restrict__ out) {
    const int wave = threadIdx.x >> 6;
    const int t    = threadIdx.x & 63;
    const int i    = blockIdx.x * 4 + wave;
    const float4* p1 = (const float4*)(z1 + (size_t)i * D_);
    const float4* p2 = (const float4*)(z2 + (size_t)i * D_);
    float4 a = p1[t], b = p2[t];
    a.x = cleanf(a.x); a.y = cleanf(a.y); a.z = cleanf(a.z); a.w = cleanf(a.w);
    b.x = cleanf(b.x); b.y = cleanf(b.y); b.z = cleanf(b.z); b.w = cleanf(b.w);

    float s1 = a.x*a.x + a.y*a.y + a.z*a.z + a.w*a.w;
    float s2 = b.x*b.x + b.y*b.y + b.z*b.z + b.w*b.w;
    float dp = a.x*b.x + a.y*b.y + a.z*b.z + a.w*b.w;
    #pragma unroll
    for (int m = 1; m < 64; m <<= 1) {
        s1 += __shfl_xor(s1, m);
        s2 += __shfl_xor(s2, m);
        dp += __shfl_xor(dp, m);
    }
    const float inv1 = 1.0f / fmaxf(sqrtf(s1), 1e-12f);
    const float inv2 = 1.0f / fmaxf(sqrtf(s2), 1e-12f);

    ushortx4 o1, o2;
    o1.x = f2bf(a.x * inv1); o1.y = f2bf(a.y * inv1); o1.z = f2bf(a.z * inv1); o1.w = f2bf(a.w * inv1);
    o2.x = f2bf(b.x * inv2); o2.y = f2bf(b.y * inv2); o2.z = f2bf(b.z * inv2); o2.w = f2bf(b.w * inv2);
    ((ushortx4*)(F + (size_t)i * D_))[t]          = o1;
    ((ushortx4*)(F + (size_t)(i + NS_) * D_))[t]  = o2;

    if (t == 0) pos[i] = dp * inv1 * inv2;       // exact fp32 positive sim
    if (t < 2)  denom[i * 2 + t] = 0.0f;         // zero denom (2 per row-pair x 4096)
    if (i == 0 && t < 32) cnt[t] = 0;            // zero rtile counters
    if (i == 0 && t == 0) out[0] = 0.0f;         // zero loss accumulator
}

// ---------------- Kernel 2: fused sim-GEMM + row exp-sums + finishers -------------------
// OCCUPANCY EXPERIMENT AT FIXED BLOCKING (vs R0): grid stays 512 = 32 rtiles x 16
// col-blocks (tile 256x512, same per-block L2 footprint, FETCH should be unchanged),
// but 512 thr / 8 waves per block. Wave w owns 2 row-strips: rows R0 + st*128 + w*16
// (st=0,1) -> afrag 64 VGPR. 2 blocks/CU x 8 waves = 16 waves/CU (4/SIMD), double R0's
// latency-hiding. LDS 66KB/block (2x32KB stage + red). __launch_bounds__(512,4) pins
// VGPR <= 128 so 2 blocks/CU co-reside. B staged via global_load_lds, XOR-swizzled,
// single 32KB buffer (R0's proven 2-barrier staging rounds).
__global__ __launch_bounds__(512, 4) void kgemm(const short* __restrict__ F,
                                                float* __restrict__ denom,
                                                int* __restrict__ cnt,
                                                const float* __restrict__ pos,
                                                float* __restrict__ out) {
    __shared__ short Bl[64 * 256];   // 32 KB staging tile [row][k], 16B chunks swizzled
    __shared__ int lastflag;
    __shared__ float red[8];

    const int rtile = blockIdx.x >> 4;   // 32 rtiles
    const int cq    = blockIdx.x & 15;   // 16 col-blocks
    const int R0 = rtile * 256;
    const int C0 = cq * 512;

    const int tid  = threadIdx.x;
    const int lane = tid & 63;
    const int wave = tid >> 6;
    const int c16  = lane & 15;
    const int quad = lane >> 4;
    const int swz  = c16 & 7;

    // staging source offsets (shorts, relative to 64-row chunk base), XOR-swizzled.
    // 2048 granules of 16B per 32KB tile; 512 threads x 4 each.
    int goff[4];
    #pragma unroll
    for (int r2 = 0; r2 < 4; ++r2) {
        int c    = tid + r2 * 512;
        int row  = c >> 5;
        int kg   = (c & 31) ^ (row & 7);
        goff[r2] = row * D_ + kg * 8;
    }

    // ---- A prologue: 4 chunks of 64 rows. Strip (w,st) has rows st*128 + w*16, which
    // live in chunk ch = st*2 + (w>>2); wave participates when (w>>2) == (ch&1).
    bf16x8 afrag[2][8];
    #pragma unroll
    for (int ch = 0; ch < 4; ++ch) {
        __syncthreads();
        const short* ga = F + (size_t)(R0 + ch * 64) * D_;
        #pragma unroll
        for (int r2 = 0; r2 < 4; ++r2)
            LDS_LOAD16(ga + goff[r2], Bl + (tid + r2 * 512) * 8);
        __syncthreads();
        const int st = ch >> 1;
        if ((wave >> 2) == (ch & 1)) {
            const int lrow = (wave & 3) * 16 + c16;        // lrow&7 == swz
            #pragma unroll
            for (int ks = 0; ks < 8; ++ks)
                afrag[st][ks] = *(const bf16x8*)(Bl + lrow * 256 +
                                                 (((ks * 4 + quad) ^ swz) * 8));
        }
    }

    float accexp[2][4];
    #pragma unroll
    for (int st = 0; st < 2; ++st)
        #pragma unroll
        for (int r = 0; r < 4; ++r) accexp[st][r] = 0.0f;

    // ---- main loop: 8 B-groups of 64 cols
    for (int it = 0; it < 8; ++it) {
        __syncthreads();                       // previous tile's reads done
        const short* gb = F + (size_t)(C0 + it * 64) * D_;
        #pragma unroll
        for (int r2 = 0; r2 < 4; ++r2)
            LDS_LOAD16(gb + goff[r2], Bl + (tid + r2 * 512) * 8);
        __syncthreads();                       // staging complete

        #pragma unroll
        for (int sub = 0; sub < 4; ++sub) {
            const int tc = sub * 16 + c16;     // tile col owned by this lane
            bf16x8 bfrag[8];
            #pragma unroll
            for (int ks = 0; ks < 8; ++ks)
                bfrag[ks] = *(const bf16x8*)(Bl + tc * 256 +
                                             (((ks * 4 + quad) ^ swz) * 8));
            f32x4 acc0 = (f32x4){0.f, 0.f, 0.f, 0.f};
            f32x4 acc1 = (f32x4){0.f, 0.f, 0.f, 0.f};
            #pragma unroll
            for (int ks = 0; ks < 8; ++ks) {
                acc0 = __builtin_amdgcn_mfma_f32_16x16x32_bf16(afrag[0][ks], bfrag[ks], acc0, 0, 0, 0);
                acc1 = __builtin_amdgcn_mfma_f32_16x16x32_bf16(afrag[1][ks], bfrag[ks], acc1, 0, 0, 0);
            }

            const int colbase = C0 + it * 64 + sub * 16;
            #pragma unroll
            for (int st = 0; st < 2; ++st) {
                const f32x4 acc = st ? acc1 : acc0;
                const int rowbase = R0 + st * 128 + wave * 16;
                if (colbase != rowbase) {            // uniform fast path
                    #pragma unroll
                    for (int r = 0; r < 4; ++r)
                        accexp[st][r] += __builtin_amdgcn_exp2f(acc[r] * EXP_SCALE);
                } else {                             // diagonal 16x16 tile
                    #pragma unroll
                    for (int r = 0; r < 4; ++r) {
                        float e = __builtin_amdgcn_exp2f(acc[r] * EXP_SCALE);
                        if (c16 == quad * 4 + r) e = 0.0f;
                        accexp[st][r] += e;
                    }
                }
            }
        }
    }

    // row sums across the 16 lanes holding each row, one atomic per row
    #pragma unroll
    for (int st = 0; st < 2; ++st)
        #pragma unroll
        for (int r = 0; r < 4; ++r) {
            float v = accexp[st][r];
            v += __shfl_xor(v, 1);
            v += __shfl_xor(v, 2);
            v += __shfl_xor(v, 4);
            v += __shfl_xor(v, 8);
            if (c16 == 0)
                atomicAdd(&denom[R0 + st * 128 + wave * 16 + quad * 4 + r], v);
        }

    // last of 16 blocks per rtile: sum(log(denom[R0..R0+256))) / M -> out (+ pos term)
    __syncthreads();
    if (tid == 0) {
        __threadfence();                              // release our denom adds
        lastflag = (atomicAdd(&cnt[rtile], 1) == 15);
    }
    __syncthreads();
    if (lastflag) {
        __threadfence();                              // acquire others' denom adds
        float p = 0.0f;
        if (tid < 256) {
            float v = atomicAdd(&denom[R0 + tid], 0.0f);  // coherent read, 256 rows
            p = __builtin_amdgcn_logf(v) * (LN2 / (float)M_);
        }
        #pragma unroll
        for (int m = 1; m < 64; m <<= 1) p += __shfl_xor(p, m);
        if (lane == 0) red[wave] = p;
        __syncthreads();
        if (tid == 0) atomicAdd(out, red[0] + red[1] + red[2] + red[3] +
                                     red[4] + red[5] + red[6] + red[7]);
        if (rtile == 0) {                             // pos ready (knorm precedes)
            __syncthreads();                          // protect red reuse
            float sp = 0.0f;
            for (int i = tid; i < NS_; i += 512) sp += pos[i];
            #pragma unroll
            for (int m = 1; m < 64; m <<= 1) sp += __shfl_xor(sp, m);
            if (lane == 0) red[wave] = sp;
            __syncthreads();
            if (tid == 0)
                atomicAdd(out, (red[0] + red[1] + red[2] + red[3] +
                                red[4] + red[5] + red[6] + red[7]) *
                               (-2.0f / (TEMP * (float)M_)));
        }
    }
}

extern "C" void kernel_launch(void* const* d_in, const int* in_sizes, int n_in,
                              void* d_out, int out_size, void* d_ws, size_t ws_size,
                              hipStream_t stream) {
    const float* z1 = (const float*)d_in[0];
    const float* z2 = (const float*)d_in[1];

    short* F     = (short*)d_ws;                                   // 4 MB
    float* denom = (float*)((char*)d_ws + (size_t)M_ * D_ * 2);    // 32 KB
    int*   cnt   = (int*)(denom + M_);                             // 128 B
    float* pos   = (float*)(cnt + 32);                             // 16 KB
    float* out   = (float*)d_out;

    knorm<<<NS_ / 4, 256, 0, stream>>>(z1, z2, F, pos, denom, cnt, out);
    kgemm<<<512, 512, 0, stream>>>(F, denom, cnt, pos, out);
}

// Round 7
// 133.916 us; speedup vs baseline: 2.2487x; 1.0947x over previous
//
#include <hip/hip_runtime.h>
#include <stdint.h>

#define NS_ 4096
#define M_  8192
#define D_  256
#define TEMP 0.07f
#define EXP_SCALE 20.61707212818536f   // log2(e)/0.07 : exp(sim/T) = exp2(sim*EXP_SCALE)
#define LN2 0.6931471805599453f

typedef short bf16x8 __attribute__((ext_vector_type(8)));
typedef float f32x4  __attribute__((ext_vector_type(4)));
typedef unsigned short ushortx4 __attribute__((ext_vector_type(4)));

static __device__ inline unsigned short f2bf(float x) {
    unsigned u = __float_as_uint(x);
    u += 0x7fffu + ((u >> 16) & 1u);
    return (unsigned short)(u >> 16);
}

static __device__ inline float cleanf(float v) {
    return __builtin_isfinite(v) ? v : 0.0f;
}

// async 16B global -> LDS (lane-contiguous LDS destination required)
#define LDS_LOAD16(gp, lp) \
    __builtin_amdgcn_global_load_lds((const __attribute__((address_space(1))) uint32_t*)(gp), \
                                     (__attribute__((address_space(3))) uint32_t*)(lp), 16, 0, 0)

// ---------------- Kernel 1: clean + normalize -> bf16 F, fp32 pos[]; zero denom/cnt/out -
// grid = NS_/4, block = 256 (one wave per paired row; 4 row-pairs per block)
__global__ __launch_bounds__(256) void knorm(const float* __restrict__ z1,
                                             const float* __restrict__ z2,
                                             short* __restrict__ F,
                                             float* __restrict__ pos,
                                             float* __restrict__ denom,
                                             int* __restrict__ cnt,
                                             float* __restrict__ out) {
    const int wave = threadIdx.x >> 6;
    const int t    = threadIdx.x & 63;
    const int i    = blockIdx.x * 4 + wave;
    const float4* p1 = (const float4*)(z1 + (size_t)i * D_);
    const float4* p2 = (const float4*)(z2 + (size_t)i * D_);
    float4 a = p1[t], b = p2[t];
    a.x = cleanf(a.x); a.y = cleanf(a.y); a.z = cleanf(a.z); a.w = cleanf(a.w);
    b.x = cleanf(b.x); b.y = cleanf(b.y); b.z = cleanf(b.z); b.w = cleanf(b.w);

    float s1 = a.x*a.x + a.y*a.y + a.z*a.z + a.w*a.w;
    float s2 = b.x*b.x + b.y*b.y + b.z*b.z + b.w*b.w;
    float dp = a.x*b.x + a.y*b.y + a.z*b.z + a.w*b.w;
    #pragma unroll
    for (int m = 1; m < 64; m <<= 1) {
        s1 += __shfl_xor(s1, m);
        s2 += __shfl_xor(s2, m);
        dp += __shfl_xor(dp, m);
    }
    const float inv1 = 1.0f / fmaxf(sqrtf(s1), 1e-12f);
    const float inv2 = 1.0f / fmaxf(sqrtf(s2), 1e-12f);

    ushortx4 o1, o2;
    o1.x = f2bf(a.x * inv1); o1.y = f2bf(a.y * inv1); o1.z = f2bf(a.z * inv1); o1.w = f2bf(a.w * inv1);
    o2.x = f2bf(b.x * inv2); o2.y = f2bf(b.y * inv2); o2.z = f2bf(b.z * inv2); o2.w = f2bf(b.w * inv2);
    ((ushortx4*)(F + (size_t)i * D_))[t]          = o1;
    ((ushortx4*)(F + (size_t)(i + NS_) * D_))[t]  = o2;

    if (t == 0) pos[i] = dp * inv1 * inv2;       // exact fp32 positive sim
    if (t < 2)  denom[i * 2 + t] = 0.0f;         // zero denom (2 per row-pair x 4096)
    if (i == 0 && t < 32) cnt[t] = 0;            // zero rtile counters
    if (i == 0 && t == 0) out[0] = 0.0f;         // zero loss accumulator
}

// ---------------- Kernel 2: 8-phase 256x256 GEMM tile (m201 template port) --------------
// grid = 1024 = 32 brow x 32 bcol (XCD-chunked swizzle), 512 thr / 8 waves (2M x 4N),
// 1 block/CU (128 KB LDS). Per-wave output 128x64: acc[8][4] f32x4. K=256 -> 4 K-tiles
// of BK=64 -> 16 phases. LDS: 2 slots x {A0,A1,B0,B1} half-tiles [128 rows][64 k],
// granule-XOR swizzled (stage source pre-swizzled; ds_read applies same XOR).
// Each phase: ds_read quadrant frags (12 or 4 x b128) -> stage 1 half-tile (2 gload_lds)
// -> barrier -> lgkmcnt(0) -> setprio(1) -> 16 MFMA -> setprio(0) -> [vmcnt(2/2/0) at
// K-tile boundaries only] -> barrier. Stage schedule verified against barrier windows:
// kt's A-halves free after its q2 phase, B-halves after q3; kt+2 staged into kt's slot
// starting one phase later. exp2 + diag mask + reduction all in epilogue (acc holds the
// full K=256 dot products).
__global__ __launch_bounds__(512, 2) void kgemm(const short* __restrict__ F,
                                                float* __restrict__ denom,
                                                int* __restrict__ cnt,
                                                const float* __restrict__ pos,
                                                float* __restrict__ out) {
    __shared__ short L[65536];          // 128 KB: [slot][A0,A1,B0,B1][128][64]
    __shared__ float red2[8];
    __shared__ int lastflag;

    const int bid = blockIdx.x;
    const int sb  = (bid & 7) * 128 + (bid >> 3);   // XCD-chunked swizzle (1024%8==0)
    const int brow = sb >> 5, bcol = sb & 31;
    const int R0g = brow * 256, C0g = bcol * 256;
    const bool isdiag = (brow == bcol);

    const int tid  = threadIdx.x;
    const int lane = tid & 63;
    const int wave = tid >> 6;
    const int c16  = lane & 15;
    const int quad = lane >> 4;
    const int swz  = c16 & 7;
    const int wm   = wave >> 2;      // wave M-row (0..1): rows wm*128..+127
    const int wn   = wave & 3;       // wave N-col (0..3): cols wn*64..+63

    f32x4 acc[8][4];
    #pragma unroll
    for (int m = 0; m < 8; ++m)
        #pragma unroll
        for (int n = 0; n < 4; ++n) acc[m][n] = (f32x4){0.f, 0.f, 0.f, 0.f};

    // stage one half-tile (128 rows x 64 k) of K-tile kt; mm: 0=A(panel R0g) 1=B(panel
    // C0g); h: row-half. LDS dest linear in lane; SOURCE pre-swizzled (inverse == same
    // XOR involution the reads apply).
    auto stage = [&](int kt, int mm, int h) {
        const int gbase = (mm ? C0g : R0g) + h * 128;
        short* ldst = L + (((kt & 1) * 4 + mm * 2 + h) * 8192);
        #pragma unroll
        for (int j = 0; j < 2; ++j) {
            const int gl  = tid + j * 512;          // granule 0..1023
            const int row = gl >> 3;
            const int g   = (gl & 7) ^ (row & 7);
            LDS_LOAD16(F + (size_t)(gbase + row) * D_ + kt * 64 + g * 8,
                       ldst + gl * 8);
        }
    };

    // ---- prologue: stage K-tiles 0,1 fully (16 loads); wait kt0 (8 newest = kt1 in flight)
    #pragma unroll
    for (int kt = 0; kt < 2; ++kt)
        #pragma unroll
        for (int mm = 0; mm < 2; ++mm)
            #pragma unroll
            for (int h = 0; h < 2; ++h)
                stage(kt, mm, h);
    asm volatile("s_waitcnt vmcnt(8)" ::: "memory");
    __builtin_amdgcn_s_barrier();

    // stage schedule per phase P (verified): P3:kt2.A0 P4:kt2.A1 P5:kt2.B0 P6:kt2.B1
    // P7:kt3.A0 P8:kt3.A1 P9:kt3.B0 P10:kt3.B1. vmcnt before end-barrier of P3/P7 (=2:
    // all but current phase's stage landed -> next kt ready) and P11 (=0: kt3 ready).
    constexpr int skt_[16] = {-1,-1,-1, 2,  2, 2, 2, 3,  3, 3, 3,-1, -1,-1,-1,-1};
    constexpr int smm_[16] = { 0, 0, 0, 0,  0, 1, 1, 0,  0, 1, 1, 0,  0, 0, 0, 0};
    constexpr int sh_ [16] = { 0, 0, 0, 0,  1, 0, 1, 0,  1, 0, 1, 0,  0, 0, 0, 0};
    constexpr int vm_ [16] = {-1,-1,-1, 2, -1,-1,-1, 2, -1,-1,-1, 0, -1,-1,-1,-1};

    bf16x8 af[4][2];                                  // A-frags held across nh=0,1
    #pragma unroll
    for (int P = 0; P < 16; ++P) {
        const int slot = (P >> 2) & 1;
        const int mh   = (P >> 1) & 1;                // quadrant order (0,0)(0,1)(1,0)(1,1)
        const int nh   = P & 1;
        const short* Ab = L + ((slot * 4 + wm) * 8192);
        const short* Bb = L + ((slot * 4 + 2 + (wn >> 1)) * 8192);

        if (nh == 0) {                                // refresh A-frags per m-half
            #pragma unroll
            for (int ml = 0; ml < 4; ++ml)
                #pragma unroll
                for (int kk = 0; kk < 2; ++kk) {
                    const int rl = mh * 64 + ml * 16 + c16;     // rl&7 == swz
                    af[ml][kk] = *(const bf16x8*)(Ab + rl * 64 +
                                                  (((kk * 4 + quad) ^ swz) * 8));
                }
        }
        bf16x8 bf[2][2];
        #pragma unroll
        for (int nl = 0; nl < 2; ++nl)
            #pragma unroll
            for (int kk = 0; kk < 2; ++kk) {
                const int cl = (wn & 1) * 64 + nh * 32 + nl * 16 + c16;
                bf[nl][kk] = *(const bf16x8*)(Bb + cl * 64 +
                                              (((kk * 4 + quad) ^ swz) * 8));
            }
        if (skt_[P] >= 0) stage(skt_[P], smm_[P], sh_[P]);

        __builtin_amdgcn_s_barrier();                 // mid: all reads/stages issued
        asm volatile("s_waitcnt lgkmcnt(0)" ::: "memory");
        __builtin_amdgcn_s_setprio(1);
        #pragma unroll
        for (int kk = 0; kk < 2; ++kk)
            #pragma unroll
            for (int ml = 0; ml < 4; ++ml)
                #pragma unroll
                for (int nl = 0; nl < 2; ++nl)
                    acc[mh * 4 + ml][nh * 2 + nl] = __builtin_amdgcn_mfma_f32_16x16x32_bf16(
                        af[ml][kk], bf[nl][kk], acc[mh * 4 + ml][nh * 2 + nl], 0, 0, 0);
        __builtin_amdgcn_s_setprio(0);
        if (vm_[P] == 2)      asm volatile("s_waitcnt vmcnt(2)" ::: "memory");
        else if (vm_[P] == 0) asm volatile("s_waitcnt vmcnt(0)" ::: "memory");
        __builtin_amdgcn_s_barrier();                 // end: phase reads complete
    }

    // ---- epilogue: exp2 + diagonal mask + row sums (once per block) --------------------
    float* redf = (float*)L;                          // reuse LDS: [256 rows][4 wn]
    #pragma unroll
    for (int m = 0; m < 8; ++m) {
        float rsum[4] = {0.f, 0.f, 0.f, 0.f};
        #pragma unroll
        for (int n = 0; n < 4; ++n) {
            const bool dmask = isdiag && ((wn >> 1) == wm) && (m == ((wn & 1) * 4 + n));
            #pragma unroll
            for (int rr = 0; rr < 4; ++rr) {
                float e = __builtin_amdgcn_exp2f(acc[m][n][rr] * EXP_SCALE);
                if (dmask && c16 == quad * 4 + rr) e = 0.0f;   // zero self-pairs
                rsum[rr] += e;
            }
        }
        #pragma unroll
        for (int rr = 0; rr < 4; ++rr) {
            float v = rsum[rr];
            v += __shfl_xor(v, 1); v += __shfl_xor(v, 2);
            v += __shfl_xor(v, 4); v += __shfl_xor(v, 8);
            if (c16 == 0)
                redf[(wm * 128 + m * 16 + quad * 4 + rr) * 4 + wn] = v;
        }
    }
    __syncthreads();
    if (tid < 256) {
        float s = redf[tid * 4 + 0] + redf[tid * 4 + 1] +
                  redf[tid * 4 + 2] + redf[tid * 4 + 3];
        atomicAdd(&denom[R0g + tid], s);
    }

    // ---- finisher: last of 32 blocks per brow sums log(denom) (+ pos term on brow 0) ---
    __syncthreads();
    if (tid == 0) {
        __threadfence();                              // release our denom adds
        lastflag = (atomicAdd(&cnt[brow], 1) == 31);
    }
    __syncthreads();
    if (lastflag) {
        __threadfence();                              // acquire others' denom adds
        float p = 0.0f;
        if (tid < 256) {
            float v = atomicAdd(&denom[R0g + tid], 0.0f);  // coherent read, 256 rows
            p = __builtin_amdgcn_logf(v) * (LN2 / (float)M_);
        }
        #pragma unroll
        for (int m = 1; m < 64; m <<= 1) p += __shfl_xor(p, m);
        if (lane == 0) red2[wave] = p;
        __syncthreads();
        if (tid == 0) atomicAdd(out, red2[0] + red2[1] + red2[2] + red2[3] +
                                     red2[4] + red2[5] + red2[6] + red2[7]);
        if (brow == 0) {                              // pos ready (knorm precedes)
            __syncthreads();                          // protect red2 reuse
            float sp = 0.0f;
            for (int i = tid; i < NS_; i += 512) sp += pos[i];
            #pragma unroll
            for (int m = 1; m < 64; m <<= 1) sp += __shfl_xor(sp, m);
            if (lane == 0) red2[wave] = sp;
            __syncthreads();
            if (tid == 0)
                atomicAdd(out, (red2[0] + red2[1] + red2[2] + red2[3] +
                                red2[4] + red2[5] + red2[6] + red2[7]) *
                               (-2.0f / (TEMP * (float)M_)));
        }
    }
}

extern "C" void kernel_launch(void* const* d_in, const int* in_sizes, int n_in,
                              void* d_out, int out_size, void* d_ws, size_t ws_size,
                              hipStream_t stream) {
    const float* z1 = (const float*)d_in[0];
    const float* z2 = (const float*)d_in[1];

    short* F     = (short*)d_ws;                                   // 4 MB
    float* denom = (float*)((char*)d_ws + (size_t)M_ * D_ * 2);    // 32 KB
    int*   cnt   = (int*)(denom + M_);                             // 128 B
    float* pos   = (float*)(cnt + 32);                             // 16 KB
    float* out   = (float*)d_out;

    knorm<<<NS_ / 4, 256, 0, stream>>>(z1, z2, F, pos, denom, cnt, out);
    kgemm<<<1024, 512, 0, stream>>>(F, denom, cnt, pos, out);
}